// Round 1
// baseline (322.448 us; speedup 1.0000x reference)
//
#include <hip/hip_runtime.h>
#include <math.h>

#define NN 2048
#define TT 1024
#define EPSF 1e-8f

struct Quat { float w, x, y, z; };

__device__ inline Quat qmul(const Quat a, const Quat b) {
    Quat r;
    r.w = a.w * b.w - a.x * b.x - a.y * b.y - a.z * b.z;
    r.x = a.w * b.x + a.x * b.w + a.y * b.z - a.z * b.y;
    r.y = a.w * b.y - a.x * b.z + a.y * b.w + a.z * b.x;
    r.z = a.w * b.z + a.x * b.y - a.y * b.x + a.z * b.w;
    return r;
}

__device__ inline Quat qexp3(float vx, float vy, float vz) {
    float n = fmaxf(sqrtf(vx * vx + vy * vy + vz * vz), EPSF);
    float s = __sinf(n) / n;
    Quat r;
    r.w = __cosf(n);
    r.x = s * vx; r.y = s * vy; r.z = s * vz;
    return r;
}

__device__ inline void qlog3(const Quat q, float& ox, float& oy, float& oz) {
    float n = fmaxf(sqrtf(q.x * q.x + q.y * q.y + q.z * q.z), EPSF);
    float c = fminf(fmaxf(q.w, -1.0f), 1.0f);
    float s = acosf(c) / n;
    ox = q.x * s; oy = q.y * s; oz = q.z * s;
}

__device__ inline float waveReduce(float v) {
    #pragma unroll
    for (int o = 32; o > 0; o >>= 1) v += __shfl_down(v, o);
    return v;
}

__global__ __launch_bounds__(256) void loss_main(
    const float* __restrict__ pred, const float* __restrict__ targ,
    const float* __restrict__ imu, double* __restrict__ acc)
{
    float s0 = 0.f, s1 = 0.f, s2 = 0.f, s3 = 0.f, s4 = 0.f, s5 = 0.f;
    const int total = NN * TT;
    const int stride = gridDim.x * blockDim.x;

    for (int idx = blockIdx.x * blockDim.x + threadIdx.x; idx < total; idx += stride) {
        const int t = idx & (TT - 1);
        const float2* pr = reinterpret_cast<const float2*>(pred) + (size_t)idx * 3;
        const float2* tg = reinterpret_cast<const float2*>(targ) + (size_t)idx * 3;
        float2 p0 = pr[0], p1 = pr[1], p2 = pr[2];
        float2 g0 = tg[0], g1 = tg[1], g2 = tg[2];

        // abs_loss partials: xyz in (p0.x,p0.y,p1.x), quat-log part (p1.y,p2.x,p2.y)
        s0 += fabsf(p0.x - g0.x) + fabsf(p0.y - g0.y) + fabsf(p1.x - g1.x);
        s1 += fabsf(p1.y - g1.y) + fabsf(p2.x - g2.x) + fabsf(p2.y - g2.y);

        if (t < TT - 1) {
            float2 n0 = pr[3], n1 = pr[4], n2 = pr[5];     // pred row t+1
            float2 h0 = tg[3], h1 = tg[4], h2 = tg[5];     // targ row t+1

            float pv0 = n0.x - p0.x, pv1 = n0.y - p0.y, pv2 = n1.x - p1.x;
            float pv3 = n1.y - p1.y, pv4 = n2.x - p2.x, pv5 = n2.y - p2.y;
            float tv0 = h0.x - g0.x, tv1 = h0.y - g0.y, tv2 = h1.x - g1.x;
            float tv3 = h1.y - g1.y, tv4 = h2.x - g2.x, tv5 = h2.y - g2.y;

            s2 += fabsf(pv0 - tv0) + fabsf(pv1 - tv1) + fabsf(pv2 - tv2);
            s3 += fabsf(pv3 - tv3) + fabsf(pv4 - tv4) + fabsf(pv5 - tv5);

            // q0 = qexp(targ[t,3:6]); q1 = qexp(targ[t+1,3:6])
            Quat q0 = qexp3(g1.y, g2.x, g2.y);
            Quat q1 = qexp3(h1.y, h2.x, h2.y);
            Quat q0i; q0i.w = q0.w; q0i.x = -q0.x; q0i.y = -q0.y; q0i.z = -q0.z;
            Quat r01 = qmul(q0i, q1);
            float tq0, tq1, tq2;
            qlog3(r01, tq0, tq1, tq2);                     // targ_imu_q

            // imu row t: 10 floats = 5 float2
            const float2* im = reinterpret_cast<const float2*>(imu) + (size_t)idx * 5;
            float2 i0 = im[0], i1 = im[1], i2 = im[2], i3 = im[3], i4 = im[4];
            float ts0 = i4.y;
            float ts1 = im[9].y;                           // imu[(idx+1)*10 + 9]
            float dt = (ts1 - ts0) * 1e-9f;

            float a0 = i0.x, a1 = i0.y, a2 = i1.x;
            float v0 = i1.y, v1 = i2.x, v2 = i2.y;
            float w0 = i3.x, w1 = i3.y, w2 = i4.x;

            float hdt2 = 0.5f * dt * dt;
            float it0 = v0 * dt + a0 * hdt2;
            float it1 = v1 * dt + a1 * hdt2;
            float it2 = v2 * dt + a2 * hdt2;
            s4 += fabsf(pv0 - it0) + fabsf(pv1 - it1) + fabsf(pv2 - it2);

            float wn = fmaxf(sqrtf(w0 * w0 + w1 * w1 + w2 * w2), EPSF);
            float half = 0.5f * wn * dt;
            float sd = __sinf(half) / wn;
            Quat dq; dq.w = __cosf(half); dq.x = w0 * sd; dq.y = w1 * sd; dq.z = w2 * sd;
            Quat nq = qmul(q0, dq);                        // new_q
            Quat m  = qmul(q0i, nq);
            float io0, io1, io2;
            qlog3(m, io0, io1, io2);                       // imu_ori_shift
            s5 += fabsf(tq0 - io0) + fabsf(tq1 - io1) + fabsf(tq2 - io2);
        }
    }

    // block reduction: wave shuffle -> LDS -> thread 0 atomics (f64)
    s0 = waveReduce(s0); s1 = waveReduce(s1); s2 = waveReduce(s2);
    s3 = waveReduce(s3); s4 = waveReduce(s4); s5 = waveReduce(s5);

    __shared__ float red[4][6];
    const int lane = threadIdx.x & 63;
    const int wid  = threadIdx.x >> 6;
    if (lane == 0) {
        red[wid][0] = s0; red[wid][1] = s1; red[wid][2] = s2;
        red[wid][3] = s3; red[wid][4] = s4; red[wid][5] = s5;
    }
    __syncthreads();
    if (threadIdx.x == 0) {
        double t0 = 0, t1 = 0, t2 = 0, t3 = 0, t4 = 0, t5 = 0;
        #pragma unroll
        for (int w = 0; w < 4; ++w) {
            t0 += red[w][0]; t1 += red[w][1]; t2 += red[w][2];
            t3 += red[w][3]; t4 += red[w][4]; t5 += red[w][5];
        }
        atomicAdd(&acc[0], t0); atomicAdd(&acc[1], t1); atomicAdd(&acc[2], t2);
        atomicAdd(&acc[3], t3); atomicAdd(&acc[4], t4); atomicAdd(&acc[5], t5);
    }
}

__global__ void loss_finalize(const double* __restrict__ acc,
                              const float* __restrict__ sax, const float* __restrict__ saq,
                              const float* __restrict__ srx, const float* __restrict__ srq,
                              float* __restrict__ out)
{
    const double inv_abs = 1.0 / ((double)NN * TT * 3);
    const double inv_vo  = 1.0 / ((double)NN * (TT - 1) * 3);
    float A = (float)(acc[0] * inv_abs);
    float B = (float)(acc[1] * inv_abs);
    float C = (float)(acc[2] * inv_vo);
    float D = (float)(acc[3] * inv_vo);
    float E = (float)(acc[4] * inv_vo);
    float F = (float)(acc[5] * inv_vo);
    float sx = sax[0], sq = saq[0], rx = srx[0], rq = srq[0];
    out[0] = expf(-sx) * A + sx + expf(-sq) * B + sq
           + expf(-rx) * (C + E) + 2.0f * rx
           + expf(-rq) * (D + F) + 2.0f * rq;
}

extern "C" void kernel_launch(void* const* d_in, const int* in_sizes, int n_in,
                              void* d_out, int out_size, void* d_ws, size_t ws_size,
                              hipStream_t stream) {
    const float* pred = (const float*)d_in[0];
    const float* targ = (const float*)d_in[1];
    const float* imu  = (const float*)d_in[2];
    const float* sax  = (const float*)d_in[3];
    const float* saq  = (const float*)d_in[4];
    const float* srx  = (const float*)d_in[5];
    const float* srq  = (const float*)d_in[6];
    float* out = (float*)d_out;
    double* acc = (double*)d_ws;

    hipMemsetAsync(acc, 0, 6 * sizeof(double), stream);

    const int block = 256;
    const int grid = 2048;   // 524288 threads, 4 positions each (grid-stride)
    loss_main<<<grid, block, 0, stream>>>(pred, targ, imu, acc);
    loss_finalize<<<1, 1, 0, stream>>>(acc, sax, saq, srx, srq, out);
}

// Round 2
// 207.399 us; speedup vs baseline: 1.5547x; 1.5547x over previous
//
#include <hip/hip_runtime.h>
#include <math.h>

#define NN 2048
#define TT 1024
#define EPSF 1e-8f

#define GRID   2048
#define BLOCK  256
#define STRIDE (GRID * BLOCK)          // 524288 threads
#define ITER   ((NN * TT) / STRIDE)    // exactly 4

struct Quat { float w, x, y, z; };

__device__ inline Quat qmul(const Quat a, const Quat b) {
    Quat r;
    r.w = a.w * b.w - a.x * b.x - a.y * b.y - a.z * b.z;
    r.x = a.w * b.x + a.x * b.w + a.y * b.z - a.z * b.y;
    r.y = a.w * b.y - a.x * b.z + a.y * b.w + a.z * b.x;
    r.z = a.w * b.z + a.x * b.y - a.y * b.x + a.z * b.w;
    return r;
}

__device__ inline Quat qexp3(float vx, float vy, float vz) {
    float n = fmaxf(sqrtf(vx * vx + vy * vy + vz * vz), EPSF);
    float s = __sinf(n) / n;
    Quat r;
    r.w = __cosf(n);
    r.x = s * vx; r.y = s * vy; r.z = s * vz;
    return r;
}

__device__ inline void qlog3(const Quat q, float& ox, float& oy, float& oz) {
    float n = fmaxf(sqrtf(q.x * q.x + q.y * q.y + q.z * q.z), EPSF);
    float c = fminf(fmaxf(q.w, -1.0f), 1.0f);
    float s = acosf(c) / n;
    ox = q.x * s; oy = q.y * s; oz = q.z * s;
}

__device__ inline float waveReduceF(float v) {
    #pragma unroll
    for (int o = 32; o > 0; o >>= 1) v += __shfl_down(v, o);
    return v;
}

__device__ inline double waveReduceD(double v) {
    #pragma unroll
    for (int o = 32; o > 0; o >>= 1) v += __shfl_down(v, o);
    return v;
}

__global__ __launch_bounds__(BLOCK) void loss_main(
    const float* __restrict__ pred, const float* __restrict__ targ,
    const float* __restrict__ imu, float* __restrict__ partial)
{
    float s0 = 0.f, s1 = 0.f, s2 = 0.f, s3 = 0.f, s4 = 0.f, s5 = 0.f;
    const int base = blockIdx.x * BLOCK + threadIdx.x;

    #pragma unroll
    for (int k = 0; k < ITER; ++k) {
        const int idx = base + k * STRIDE;
        const int t = idx & (TT - 1);
        const float2* pr = reinterpret_cast<const float2*>(pred) + (size_t)idx * 3;
        const float2* tg = reinterpret_cast<const float2*>(targ) + (size_t)idx * 3;
        float2 p0 = pr[0], p1 = pr[1], p2 = pr[2];
        float2 g0 = tg[0], g1 = tg[1], g2 = tg[2];

        // abs_loss partials: xyz in (p0.x,p0.y,p1.x), rot part (p1.y,p2.x,p2.y)
        s0 += fabsf(p0.x - g0.x) + fabsf(p0.y - g0.y) + fabsf(p1.x - g1.x);
        s1 += fabsf(p1.y - g1.y) + fabsf(p2.x - g2.x) + fabsf(p2.y - g2.y);

        if (t < TT - 1) {
            float2 n0 = pr[3], n1 = pr[4], n2 = pr[5];     // pred row t+1
            float2 h0 = tg[3], h1 = tg[4], h2 = tg[5];     // targ row t+1

            float pv0 = n0.x - p0.x, pv1 = n0.y - p0.y, pv2 = n1.x - p1.x;
            float pv3 = n1.y - p1.y, pv4 = n2.x - p2.x, pv5 = n2.y - p2.y;
            float tv0 = h0.x - g0.x, tv1 = h0.y - g0.y, tv2 = h1.x - g1.x;
            float tv3 = h1.y - g1.y, tv4 = h2.x - g2.x, tv5 = h2.y - g2.y;

            s2 += fabsf(pv0 - tv0) + fabsf(pv1 - tv1) + fabsf(pv2 - tv2);
            s3 += fabsf(pv3 - tv3) + fabsf(pv4 - tv4) + fabsf(pv5 - tv5);

            // q0 = qexp(targ[t,3:6]); q1 = qexp(targ[t+1,3:6])
            Quat q0 = qexp3(g1.y, g2.x, g2.y);
            Quat q1 = qexp3(h1.y, h2.x, h2.y);
            Quat q0i; q0i.w = q0.w; q0i.x = -q0.x; q0i.y = -q0.y; q0i.z = -q0.z;
            Quat r01 = qmul(q0i, q1);
            float tq0, tq1, tq2;
            qlog3(r01, tq0, tq1, tq2);                     // targ_imu_q

            // imu row t: 10 floats = 5 float2
            const float2* im = reinterpret_cast<const float2*>(imu) + (size_t)idx * 5;
            float2 i0 = im[0], i1 = im[1], i2 = im[2], i3 = im[3], i4 = im[4];
            float ts0 = i4.y;
            float ts1 = im[9].y;                           // imu[(idx+1)*10 + 9]
            float dt = (ts1 - ts0) * 1e-9f;

            float a0 = i0.x, a1 = i0.y, a2 = i1.x;
            float v0 = i1.y, v1 = i2.x, v2 = i2.y;
            float w0 = i3.x, w1 = i3.y, w2 = i4.x;

            float hdt2 = 0.5f * dt * dt;
            float it0 = v0 * dt + a0 * hdt2;
            float it1 = v1 * dt + a1 * hdt2;
            float it2 = v2 * dt + a2 * hdt2;
            s4 += fabsf(pv0 - it0) + fabsf(pv1 - it1) + fabsf(pv2 - it2);

            float wn = fmaxf(sqrtf(w0 * w0 + w1 * w1 + w2 * w2), EPSF);
            float half = 0.5f * wn * dt;
            float sd = __sinf(half) / wn;
            Quat dq; dq.w = __cosf(half); dq.x = w0 * sd; dq.y = w1 * sd; dq.z = w2 * sd;
            Quat nq = qmul(q0, dq);                        // new_q
            Quat m  = qmul(q0i, nq);
            float io0, io1, io2;
            qlog3(m, io0, io1, io2);                       // imu_ori_shift
            s5 += fabsf(tq0 - io0) + fabsf(tq1 - io1) + fabsf(tq2 - io2);
        }
    }

    // block reduction: wave shuffle -> LDS -> per-block partial store (NO atomics)
    s0 = waveReduceF(s0); s1 = waveReduceF(s1); s2 = waveReduceF(s2);
    s3 = waveReduceF(s3); s4 = waveReduceF(s4); s5 = waveReduceF(s5);

    __shared__ float red[4][6];
    const int lane = threadIdx.x & 63;
    const int wid  = threadIdx.x >> 6;
    if (lane == 0) {
        red[wid][0] = s0; red[wid][1] = s1; red[wid][2] = s2;
        red[wid][3] = s3; red[wid][4] = s4; red[wid][5] = s5;
    }
    __syncthreads();
    if (threadIdx.x < 6) {
        const int c = threadIdx.x;
        partial[(size_t)blockIdx.x * 6 + c] = red[0][c] + red[1][c] + red[2][c] + red[3][c];
    }
}

__global__ __launch_bounds__(256) void loss_finalize(
    const float* __restrict__ partial,
    const float* __restrict__ sax, const float* __restrict__ saq,
    const float* __restrict__ srx, const float* __restrict__ srq,
    float* __restrict__ out)
{
    double t0 = 0, t1 = 0, t2 = 0, t3 = 0, t4 = 0, t5 = 0;
    for (int r = threadIdx.x; r < GRID; r += 256) {
        const float* p = partial + (size_t)r * 6;
        t0 += p[0]; t1 += p[1]; t2 += p[2];
        t3 += p[3]; t4 += p[4]; t5 += p[5];
    }
    t0 = waveReduceD(t0); t1 = waveReduceD(t1); t2 = waveReduceD(t2);
    t3 = waveReduceD(t3); t4 = waveReduceD(t4); t5 = waveReduceD(t5);

    __shared__ double red[4][6];
    const int lane = threadIdx.x & 63;
    const int wid  = threadIdx.x >> 6;
    if (lane == 0) {
        red[wid][0] = t0; red[wid][1] = t1; red[wid][2] = t2;
        red[wid][3] = t3; red[wid][4] = t4; red[wid][5] = t5;
    }
    __syncthreads();
    if (threadIdx.x == 0) {
        double a0 = 0, a1 = 0, a2 = 0, a3 = 0, a4 = 0, a5 = 0;
        #pragma unroll
        for (int w = 0; w < 4; ++w) {
            a0 += red[w][0]; a1 += red[w][1]; a2 += red[w][2];
            a3 += red[w][3]; a4 += red[w][4]; a5 += red[w][5];
        }
        const double inv_abs = 1.0 / ((double)NN * TT * 3);
        const double inv_vo  = 1.0 / ((double)NN * (TT - 1) * 3);
        float A = (float)(a0 * inv_abs);
        float B = (float)(a1 * inv_abs);
        float C = (float)(a2 * inv_vo);
        float D = (float)(a3 * inv_vo);
        float E = (float)(a4 * inv_vo);
        float F = (float)(a5 * inv_vo);
        float sx = sax[0], sq = saq[0], rx = srx[0], rq = srq[0];
        out[0] = expf(-sx) * A + sx + expf(-sq) * B + sq
               + expf(-rx) * (C + E) + 2.0f * rx
               + expf(-rq) * (D + F) + 2.0f * rq;
    }
}

extern "C" void kernel_launch(void* const* d_in, const int* in_sizes, int n_in,
                              void* d_out, int out_size, void* d_ws, size_t ws_size,
                              hipStream_t stream) {
    const float* pred = (const float*)d_in[0];
    const float* targ = (const float*)d_in[1];
    const float* imu  = (const float*)d_in[2];
    const float* sax  = (const float*)d_in[3];
    const float* saq  = (const float*)d_in[4];
    const float* srx  = (const float*)d_in[5];
    const float* srq  = (const float*)d_in[6];
    float* out = (float*)d_out;
    float* partial = (float*)d_ws;   // GRID * 6 floats = 48 KB

    loss_main<<<GRID, BLOCK, 0, stream>>>(pred, targ, imu, partial);
    loss_finalize<<<1, 256, 0, stream>>>(partial, sax, saq, srx, srq, out);
}